// Round 19
// baseline (65.181 us; speedup 1.0000x reference)
//
#include <hip/hip_runtime.h>
#include <hip/hip_fp16.h>

// Joint bilateral filter block — persistent producer/consumer wave
// specialization, double-buffered 64-patch fp16 tiles, deep-batched staging.
// x (1,1,20,96,96) f32; guide_im (N,343) f32, N = 16*96*96 = 147456;
// out n = dd*9216 + h*96 + w uses x depths dd+1..dd+3, H/W zero-pad.
//
// History: r17 deep-batch staging = 46.1us (MLP was the limiter; Little's
// law). r18 ring = 49.5 (steady-state depth fell back to 2 rows). Remaining
// gap to ~30us BW floor = stage/conv phase serialization (3 blocks drift
// into lockstep). This round: 1 block/CU, 9 tiles each, wave 3 = producer
// (deep-batched stage of tile t+1 into the other buffer), waves 0-2 =
// consumers ({9,8,8} task split over tile t), wave 0 also finishes tile
// t-1's combine. ONE barrier per tile. LDS 128,000B dynamic (2 tiles +
// f32 partials) via hipFuncSetAttribute.

#define NPATCH   147456
#define TPB      256
#define PPB      64
#define NTILES   (NPATCH / PPB)       // 2304
#define NBLOCK   256
#define TPBLK    (NTILES / NBLOCK)    // 9 tiles per block
#define PATCH_H  392                  // halves per patch (49 rows * 8)
#define PATCH_D  196                  // dwords per patch
#define NROWS    (PPB * 49)           // 3136 rows per tile
#define BUF_H    (PPB * PATCH_H)      // 25088 halves = 50176 B per tile buf
#define SMEM_BYTES (2 * BUF_H * 2 + 2 * 2 * PPB * 27 * 4)   // 128,000 B

typedef float f4u __attribute__((ext_vector_type(4), aligned(4)));
typedef float f2u __attribute__((ext_vector_type(2), aligned(4)));

// ---------------- Kernel A: domain branch (runs once, 1 block) --------------
__global__ __launch_bounds__(128) void domain_branch_kernel(
    const float* __restrict__ dn,
    const float* __restrict__ w1, const float* __restrict__ b1,
    const float* __restrict__ w2, const float* __restrict__ b2,
    float* __restrict__ dom_out)
{
    __shared__ float s_in[344];
    __shared__ float s_c1[128];
    const int t = threadIdx.x;
    for (int idx = t; idx < 343; idx += 128) s_in[idx] = dn[idx];
    __syncthreads();
    if (t < 125) {
        const int i = t / 25, j = (t / 5) % 5, k = t % 5;
        float acc = b1[0];
        const float* base = &s_in[i * 49 + j * 7 + k];
#pragma unroll
        for (int dz = 0; dz < 3; ++dz)
#pragma unroll
            for (int dy = 0; dy < 3; ++dy)
#pragma unroll
                for (int dx = 0; dx < 3; ++dx)
                    acc = fmaf(base[dz * 49 + dy * 7 + dx], w1[dz * 9 + dy * 3 + dx], acc);
        s_c1[t] = fmaxf(acc, 0.f);
    }
    __syncthreads();
    if (t < 27) {
        const int dz = t / 9, dy = (t / 3) % 3, dx = t % 3;
        float acc = b2[0];
#pragma unroll
        for (int u = 0; u < 3; ++u)
#pragma unroll
            for (int v = 0; v < 3; ++v)
#pragma unroll
                for (int q = 0; q < 3; ++q)
                    acc = fmaf(s_c1[(dz + u) * 25 + (dy + v) * 5 + (dx + q)],
                               w2[u * 9 + v * 3 + q], acc);
        dom_out[t] = fmaxf(acc, 0.f);
    }
}

// ---------------- helpers ----------------
__device__ __forceinline__ float h2f_lo(unsigned int q) {
    return __half2float(__ushort_as_half((unsigned short)(q & 0xffffu)));
}
__device__ __forceinline__ float h2f_hi(unsigned int q) {
    return __half2float(__ushort_as_half((unsigned short)(q >> 16)));
}
__device__ __forceinline__ unsigned int pkh(float lo, float hi) {
    return __builtin_bit_cast(unsigned int, __builtin_amdgcn_cvt_pkrtz(lo, hi));
}

__device__ __forceinline__ void load_row(const unsigned int* __restrict__ P, float* d,
                                         int zi, int y) {
    const int d0 = zi * 28 + y * 4;        // dword offset, 16B aligned
    const uint4 q = *reinterpret_cast<const uint4*>(P + d0);
    d[0] = h2f_lo(q.x); d[1] = h2f_hi(q.x);
    d[2] = h2f_lo(q.y); d[3] = h2f_hi(q.y);
    d[4] = h2f_lo(q.z); d[5] = h2f_hi(q.z);
    d[6] = h2f_lo(q.w);
}

// Run conv1+fused-conv2 row-tasks (i,j) from (IB,JB) to (IE,JE) inclusive,
// accumulating into a2 (partial).
template<int IB, int JB, int IE, int JE>
__device__ __forceinline__ void run_tasks(const unsigned int* __restrict__ P,
                                          const float* __restrict__ w1, float bb1,
                                          const float* __restrict__ w2,
                                          float (&a2)[3][3][3])
{
#pragma unroll
    for (int i = IB; i <= IE; ++i) {
        float rw[3][3][7];
        const int j0 = (i == IB) ? JB : 0;
        const int j1 = (i == IE) ? JE : 4;
#pragma unroll
        for (int j = j0; j <= j1; ++j) {
            if (j == j0) {
#pragma unroll
                for (int u = 0; u < 3; ++u)
#pragma unroll
                    for (int dy = 0; dy < 3; ++dy)
                        load_row(P, rw[u][(j + dy) % 3], i + u, j + dy);
            } else {
#pragma unroll
                for (int u = 0; u < 3; ++u)
                    load_row(P, rw[u][(j + 2) % 3], i + u, j + 2);
            }

            float c1r[5];
#pragma unroll
            for (int k = 0; k < 5; ++k) {
                float a = bb1;
#pragma unroll
                for (int u = 0; u < 3; ++u)
#pragma unroll
                    for (int v = 0; v < 3; ++v) {
                        const float* rr = rw[u][(j + v) % 3];
#pragma unroll
                        for (int w = 0; w < 3; ++w)
                            a = fmaf(rr[k + w], w1[u * 9 + v * 3 + w], a);
                    }
                c1r[k] = fmaxf(a, 0.f);
            }

#pragma unroll
            for (int dz2 = 0; dz2 < 3; ++dz2) {
                const int u2 = i - dz2;
                if (u2 >= 0 && u2 < 3) {
#pragma unroll
                    for (int v2 = 0; v2 < 3; ++v2) {
                        const int dy2 = j - v2;
                        if (dy2 >= 0 && dy2 < 3) {
#pragma unroll
                            for (int dx2 = 0; dx2 < 3; ++dx2)
#pragma unroll
                                for (int q = 0; q < 3; ++q)
                                    a2[dz2][dy2][dx2] =
                                        fmaf(c1r[dx2 + q],
                                             w2[u2 * 9 + v2 * 3 + q],
                                             a2[dz2][dy2][dx2]);
                        }
                    }
                }
            }
        }
    }
}

// Producer chunk: lane's rows R = l + k*64 for k in [K0, K0+CNT); deep-batch
// all loads, fence, then convert+write. (p, rem) walker advanced in place.
template<int CNT>
__device__ __forceinline__ void stage_chunk(const float* __restrict__ srcf,
                                            unsigned int* __restrict__ dwbuf,
                                            int& p, int& rem) {
    f4u A[CNT]; f2u B[CNT]; float C[CNT];
    int pl = p, rl = rem;
#pragma unroll
    for (int k = 0; k < CNT; ++k) {
        const float* s = srcf + pl * 343 + rl * 7;
        A[k] = *reinterpret_cast<const f4u*>(s);
        B[k] = *reinterpret_cast<const f2u*>(s + 4);
        C[k] = s[6];
        pl += 1; rl += 15; if (rl >= 49) { rl -= 49; pl += 1; }
    }
    __builtin_amdgcn_sched_barrier(0);      // keep all loads above the writes
    pl = p; rl = rem;
#pragma unroll
    for (int k = 0; k < CNT; ++k) {
        uint4 q;
        q.x = pkh(A[k].x, A[k].y); q.y = pkh(A[k].z, A[k].w);
        q.z = pkh(B[k].x, B[k].y); q.w = pkh(C[k], 0.f);
        *reinterpret_cast<uint4*>(dwbuf + pl * PATCH_D + rl * 4) = q;
        pl += 1; rl += 15; if (rl >= 49) { rl -= 49; pl += 1; }
    }
    p = pl; rem = rl;
}

// ---------------- Kernel B: persistent producer/consumer -------------------
__global__ __launch_bounds__(TPB, 1) void jbf_main_kernel(
    const float* __restrict__ guide, const float* __restrict__ x,
    const float* __restrict__ w1, const float* __restrict__ b1,
    const float* __restrict__ w2, const float* __restrict__ b2,
    const float* __restrict__ dom, float* __restrict__ out)
{
    extern __shared__ unsigned char smem[];
    unsigned short* buf  = reinterpret_cast<unsigned short*>(smem);     // [2][BUF_H]
    float*          part = reinterpret_cast<float*>(smem + 2 * BUF_H * 2);
    // part layout: [parity][wv(0..1)][lane][27]

    const int tid   = threadIdx.x;
    const int wid   = tid >> 6;
    const int lane  = tid & 63;
    const int tile0 = blockIdx.x * TPBLK;

    const float bb1 = b1[0];
    const float bb2 = b2[0];

    // ---- prologue: ALL waves deep-stage tile 0 into buf parity 0 (r17) ----
    {
        const float* __restrict__ srcf = guide + (size_t)tile0 * (PPB * 343);
        unsigned int* __restrict__ tdw = reinterpret_cast<unsigned int*>(buf);
        f4u A[13]; f2u B[13]; float C[13];
#pragma unroll
        for (int rd = 0; rd < 13; ++rd) {
            int idx = tid + rd * TPB;
            if (idx > NROWS - 1) idx = NROWS - 1;
            const int p = idx / 49, r = idx - p * 49;
            const float* s = srcf + p * 343 + r * 7;
            A[rd] = *reinterpret_cast<const f4u*>(s);
            B[rd] = *reinterpret_cast<const f2u*>(s + 4);
            C[rd] = s[6];
        }
        __builtin_amdgcn_sched_barrier(0);
#pragma unroll
        for (int rd = 0; rd < 13; ++rd) {
            if (rd < 12 || tid < NROWS - 12 * TPB) {
                const int idx = tid + rd * TPB;
                const int p = idx / 49, r = idx - p * 49;
                uint4 q;
                q.x = pkh(A[rd].x, A[rd].y); q.y = pkh(A[rd].z, A[rd].w);
                q.z = pkh(B[rd].x, B[rd].y); q.w = pkh(C[rd], 0.f);
                *reinterpret_cast<uint4*>(tdw + p * PATCH_D + r * 4) = q;
            }
        }
    }
    __syncthreads();

    float a2[3][3][3];      // wave 0: persists across iterations for combine

#pragma unroll 1
    for (int t = 0; t < TPBLK; ++t) {
        unsigned int* curd = reinterpret_cast<unsigned int*>(buf + (t & 1) * BUF_H);

        if (wid == 3) {
            // -------- producer: stage tile t+1 into the other buffer -------
            if (t + 1 < TPBLK) {
                const float* __restrict__ srcf =
                    guide + (size_t)(tile0 + t + 1) * (PPB * 343);
                unsigned int* __restrict__ nxtd =
                    reinterpret_cast<unsigned int*>(buf + ((t + 1) & 1) * BUF_H);
                int p = lane / 49, rem = lane - (lane / 49) * 49;
                stage_chunk<17>(srcf, nxtd, p, rem);
                stage_chunk<16>(srcf, nxtd, p, rem);
                stage_chunk<16>(srcf, nxtd, p, rem);
            }
        } else if (wid == 0) {
            // -------- consumer 0: finish tile t-1, then conv tile t --------
            if (t > 0) {
                const int n   = (tile0 + t - 1) * PPB + lane;
                const float* pb = part + ((t - 1) & 1) * (2 * PPB * 27);
                const int dd  = n / 9216;
                const int rm  = n - dd * 9216;
                const int h   = rm / 96;
                const int w_  = rm - h * 96;
                float num = 0.f, den = 0.f;
#pragma unroll
                for (int dz = 0; dz < 3; ++dz)
#pragma unroll
                    for (int dy = 0; dy < 3; ++dy)
#pragma unroll
                        for (int dx = 0; dx < 3; ++dx) {
                            const int tt = dz * 9 + dy * 3 + dx;
                            const float r2 = fmaxf(a2[dz][dy][dx]
                                                   + pb[(0 * PPB + lane) * 27 + tt]
                                                   + pb[(1 * PPB + lane) * 27 + tt], 0.f);
                            const float wt = fmaf(dom[tt], r2, 1e-10f);
                            const int yy = h - 1 + dy, xx = w_ - 1 + dx;
                            float xv = 0.f;
                            if (yy >= 0 && yy < 96 && xx >= 0 && xx < 96)
                                xv = x[(dd + 1 + dz) * 9216 + yy * 96 + xx];
                            num = fmaf(wt, xv, num);
                            den += wt;
                        }
                out[n] = num / den;
            }
#pragma unroll
            for (int a = 0; a < 3; ++a)
#pragma unroll
                for (int b = 0; b < 3; ++b)
#pragma unroll
                    for (int c = 0; c < 3; ++c) a2[a][b][c] = bb2;
            run_tasks<0, 0, 1, 3>(curd + lane * PATCH_D, w1, bb1, w2, a2); // 9
        } else {
            // -------- consumers 1,2: conv tile t, write partials -----------
            float al[3][3][3];
#pragma unroll
            for (int a = 0; a < 3; ++a)
#pragma unroll
                for (int b = 0; b < 3; ++b)
#pragma unroll
                    for (int c = 0; c < 3; ++c) al[a][b][c] = 0.f;
            if (wid == 1) run_tasks<1, 4, 3, 1>(curd + lane * PATCH_D, w1, bb1, w2, al); // 8
            else          run_tasks<3, 2, 4, 4>(curd + lane * PATCH_D, w1, bb1, w2, al); // 8
            float* pb = part + (t & 1) * (2 * PPB * 27) + ((wid - 1) * PPB + lane) * 27;
#pragma unroll
            for (int tt = 0; tt < 27; ++tt)
                pb[tt] = al[tt / 9][(tt / 3) % 3][tt % 3];
        }
        __syncthreads();
    }

    // ---- epilogue: combine last tile ----
    if (wid == 0) {
        const int t = TPBLK - 1;
        const int n   = (tile0 + t) * PPB + lane;
        const float* pb = part + (t & 1) * (2 * PPB * 27);
        const int dd  = n / 9216;
        const int rm  = n - dd * 9216;
        const int h   = rm / 96;
        const int w_  = rm - h * 96;
        float num = 0.f, den = 0.f;
#pragma unroll
        for (int dz = 0; dz < 3; ++dz)
#pragma unroll
            for (int dy = 0; dy < 3; ++dy)
#pragma unroll
                for (int dx = 0; dx < 3; ++dx) {
                    const int tt = dz * 9 + dy * 3 + dx;
                    const float r2 = fmaxf(a2[dz][dy][dx]
                                           + pb[(0 * PPB + lane) * 27 + tt]
                                           + pb[(1 * PPB + lane) * 27 + tt], 0.f);
                    const float wt = fmaf(dom[tt], r2, 1e-10f);
                    const int yy = h - 1 + dy, xx = w_ - 1 + dx;
                    float xv = 0.f;
                    if (yy >= 0 && yy < 96 && xx >= 0 && xx < 96)
                        xv = x[(dd + 1 + dz) * 9216 + yy * 96 + xx];
                    num = fmaf(wt, xv, num);
                    den += wt;
                }
        out[n] = num / den;
    }
}

extern "C" void kernel_launch(void* const* d_in, const int* in_sizes, int n_in,
                              void* d_out, int out_size, void* d_ws, size_t ws_size,
                              hipStream_t stream) {
    const float* x     = (const float*)d_in[0];
    const float* dn    = (const float*)d_in[1];
    const float* guide = (const float*)d_in[2];
    const float* w1_d  = (const float*)d_in[3];
    const float* b1_d  = (const float*)d_in[4];
    const float* w2_d  = (const float*)d_in[5];
    const float* b2_d  = (const float*)d_in[6];
    const float* w1_r  = (const float*)d_in[7];
    const float* b1_r  = (const float*)d_in[8];
    const float* w2_r  = (const float*)d_in[9];
    const float* b2_r  = (const float*)d_in[10];
    float* out = (float*)d_out;
    float* dom = (float*)d_ws;   // 27 floats of scratch

    // allow 128,000 B of dynamic LDS (idempotent; capture-safe host call)
    hipFuncSetAttribute((const void*)jbf_main_kernel,
                        hipFuncAttributeMaxDynamicSharedMemorySize, SMEM_BYTES);

    domain_branch_kernel<<<1, 128, 0, stream>>>(dn, w1_d, b1_d, w2_d, b2_d, dom);
    jbf_main_kernel<<<NBLOCK, TPB, SMEM_BYTES, stream>>>(guide, x, w1_r, b1_r,
                                                         w2_r, b2_r, dom, out);
}

// Round 20
// 47.771 us; speedup vs baseline: 1.3644x; 1.3644x over previous
//
#include <hip/hip_runtime.h>
#include <hip/hip_fp16.h>

// Joint bilateral filter block — 4-wave cooperative, thread-per-patch,
// row-aligned fp16 LDS tile; deep-batched staging (r17) + fully
// DISTRIBUTED combine (tap-split across all 4 waves).
// x (1,1,20,96,96) f32; guide_im (N,343) f32, N = 16*96*96 = 147456;
// out n = dd*9216 + h*96 + w uses x depths dd+1..dd+3, H/W zero-pad.
//
// History: r17 deep-batch staging = 46.1us best. Accounting: stage ~32us
// (at BW ceiling during the stage phase), conv ~10us, combine+barriers ~4us,
// nearly serial. r18 ring 49.5, r19 producer/consumer 65.2. This round
// removes the serial wave0-only combine: all 4 waves write partials (4 sets),
// each wave combines a tap range {7,7,7,6}, num/den exchanged via LDS,
// wave0 does the final divide.

#define NPATCH 147456
#define TPB     256        // 4 waves
#define PPB      64        // patches per block (one per lane, all waves share)
#define NBLK   (NPATCH / PPB)   // 2304
#define ROW_H     8        // halves per row: 7 data + 1 pad (16 B aligned)
#define PATCH_H 392        // 49 rows * 8 halves = 784 B per patch
#define PATCH_D 196        // dwords per patch
#define NROWS  (PPB * 49)  // 3136 rows per tile
#define NRD      13        // staging rounds: 12 full + 1 partial (64 rows)

typedef float f4u __attribute__((ext_vector_type(4), aligned(4)));
typedef float f2u __attribute__((ext_vector_type(2), aligned(4)));

// ---------------- Kernel A: domain branch (runs once, 1 block) --------------
__global__ __launch_bounds__(128) void domain_branch_kernel(
    const float* __restrict__ dn,
    const float* __restrict__ w1, const float* __restrict__ b1,
    const float* __restrict__ w2, const float* __restrict__ b2,
    float* __restrict__ dom_out)
{
    __shared__ float s_in[344];
    __shared__ float s_c1[128];
    const int t = threadIdx.x;
    for (int idx = t; idx < 343; idx += 128) s_in[idx] = dn[idx];
    __syncthreads();
    if (t < 125) {
        const int i = t / 25, j = (t / 5) % 5, k = t % 5;
        float acc = b1[0];
        const float* base = &s_in[i * 49 + j * 7 + k];
#pragma unroll
        for (int dz = 0; dz < 3; ++dz)
#pragma unroll
            for (int dy = 0; dy < 3; ++dy)
#pragma unroll
                for (int dx = 0; dx < 3; ++dx)
                    acc = fmaf(base[dz * 49 + dy * 7 + dx], w1[dz * 9 + dy * 3 + dx], acc);
        s_c1[t] = fmaxf(acc, 0.f);
    }
    __syncthreads();
    if (t < 27) {
        const int dz = t / 9, dy = (t / 3) % 3, dx = t % 3;
        float acc = b2[0];
#pragma unroll
        for (int u = 0; u < 3; ++u)
#pragma unroll
            for (int v = 0; v < 3; ++v)
#pragma unroll
                for (int q = 0; q < 3; ++q)
                    acc = fmaf(s_c1[(dz + u) * 25 + (dy + v) * 5 + (dx + q)],
                               w2[u * 9 + v * 3 + q], acc);
        dom_out[t] = fmaxf(acc, 0.f);
    }
}

// ---------------- helpers ----------------
__device__ __forceinline__ float h2f_lo(unsigned int q) {
    return __half2float(__ushort_as_half((unsigned short)(q & 0xffffu)));
}
__device__ __forceinline__ float h2f_hi(unsigned int q) {
    return __half2float(__ushort_as_half((unsigned short)(q >> 16)));
}
__device__ __forceinline__ unsigned int pkh(float lo, float hi) {
    return __builtin_bit_cast(unsigned int, __builtin_amdgcn_cvt_pkrtz(lo, hi));
}

// Load row y of absolute z-slice zi (16B-aligned, 8-half rows) into d[0..6].
__device__ __forceinline__ void load_row(const unsigned int* __restrict__ P, float* d,
                                         int zi, int y) {
    const int d0 = zi * 28 + y * 4;        // dword offset, multiple of 4 -> 16B
    const uint4 q = *reinterpret_cast<const uint4*>(P + d0);
    d[0] = h2f_lo(q.x); d[1] = h2f_hi(q.x);
    d[2] = h2f_lo(q.y); d[3] = h2f_hi(q.y);
    d[4] = h2f_lo(q.z); d[5] = h2f_hi(q.z);
    d[6] = h2f_lo(q.w);
}

// Run conv1+fused-conv2 row-tasks (i,j) from (IB,JB) to (IE,JE) inclusive.
template<int IB, int JB, int IE, int JE>
__device__ __forceinline__ void run_tasks(const unsigned int* __restrict__ P,
                                          const float* __restrict__ w1, float bb1,
                                          const float* __restrict__ w2,
                                          float (&a2)[3][3][3])
{
#pragma unroll
    for (int i = IB; i <= IE; ++i) {              // c1 z-slab (input slices i..i+2)
        float rw[3][3][7];                        // [u][y%3][k]
        const int j0 = (i == IB) ? JB : 0;
        const int j1 = (i == IE) ? JE : 4;
#pragma unroll
        for (int j = j0; j <= j1; ++j) {
            if (j == j0) {
#pragma unroll
                for (int u = 0; u < 3; ++u)
#pragma unroll
                    for (int dy = 0; dy < 3; ++dy)
                        load_row(P, rw[u][(j + dy) % 3], i + u, j + dy);
            } else {
#pragma unroll
                for (int u = 0; u < 3; ++u)
                    load_row(P, rw[u][(j + 2) % 3], i + u, j + 2);
            }

            // c1 row (i, j, k=0..4)
            float c1r[5];
#pragma unroll
            for (int k = 0; k < 5; ++k) {
                float a = bb1;
#pragma unroll
                for (int u = 0; u < 3; ++u)
#pragma unroll
                    for (int v = 0; v < 3; ++v) {
                        const float* rr = rw[u][(j + v) % 3];
#pragma unroll
                        for (int w = 0; w < 3; ++w)
                            a = fmaf(rr[k + w], w1[u * 9 + v * 3 + w], a);
                    }
                c1r[k] = fmaxf(a, 0.f);
            }

            // fused conv2 accumulation
#pragma unroll
            for (int dz2 = 0; dz2 < 3; ++dz2) {
                const int u2 = i - dz2;
                if (u2 >= 0 && u2 < 3) {
#pragma unroll
                    for (int v2 = 0; v2 < 3; ++v2) {
                        const int dy2 = j - v2;
                        if (dy2 >= 0 && dy2 < 3) {
#pragma unroll
                            for (int dx2 = 0; dx2 < 3; ++dx2)
#pragma unroll
                                for (int q = 0; q < 3; ++q)
                                    a2[dz2][dy2][dx2] =
                                        fmaf(c1r[dx2 + q],
                                             w2[u2 * 9 + v2 * 3 + q],
                                             a2[dz2][dy2][dx2]);
                        }
                    }
                }
            }
        }
    }
}

// ---------------- Kernel B: range branch + bilateral combine ----------------
__global__ __launch_bounds__(TPB, 2) void jbf_main_kernel(
    const float* __restrict__ guide, const float* __restrict__ x,
    const float* __restrict__ w1, const float* __restrict__ b1,
    const float* __restrict__ w2, const float* __restrict__ b2,
    const float* __restrict__ dom, float* __restrict__ out)
{
    // combine buffers alias the (dead-by-then) patch tile: 50,176 B total
    union SM {
        unsigned short tile[PPB * PATCH_H];   // 50,176 B
        struct {
            float part[4][PPB][27];           // 27,648 B (all 4 waves)
            float nd[4][PPB][2];              //  2,048 B (num/den partials)
        } c;
    };
    __shared__ SM sm;

    const int tid  = threadIdx.x;
    const int wid  = tid >> 6;      // wave 0..3
    const int lane = tid & 63;      // patch owned by this thread
    const int blk  = blockIdx.x;
    const int n    = blk * PPB + lane;

    // ---- per-wave tap range {7,7,7,6} + early scattered x loads ----
    const int t0   = wid * 7;
    const int tcnt = (wid == 3) ? 6 : 7;
    const int dd   = n / 9216;
    const int rem  = n - dd * 9216;
    const int h    = rem / 96;
    const int w_   = rem - h * 96;

    float xv[7];
#pragma unroll
    for (int k = 0; k < 7; ++k) {
        if (k < tcnt) {
            const int tt = t0 + k;
            const int dz = tt / 9, r9 = tt - dz * 9;
            const int dy = r9 / 3,  dx = r9 - dy * 3;
            const int yy = h - 1 + dy, xx = w_ - 1 + dx;
            float v = 0.f;
            if (yy >= 0 && yy < 96 && xx >= 0 && xx < 96)
                v = x[(dd + 1 + dz) * 9216 + yy * 96 + xx];
            xv[k] = v;
        }
    }

    // ========= stage 64 patches -> fp16 LDS: deep-batched two-pass =========
    {
        const float* __restrict__ srcf = guide + (size_t)blk * (PPB * 343);
        unsigned int* __restrict__ tdw = reinterpret_cast<unsigned int*>(sm.tile);

        f4u A[NRD]; f2u B[NRD]; float C[NRD];
#pragma unroll
        for (int rd = 0; rd < NRD; ++rd) {
            int idx = tid + rd * TPB;
            if (idx > NROWS - 1) idx = NROWS - 1;   // clamp (dup load, rd==12)
            const int p = idx / 49, r = idx - p * 49;
            const float* s = srcf + p * 343 + r * 7;
            A[rd] = *reinterpret_cast<const f4u*>(s);
            B[rd] = *reinterpret_cast<const f2u*>(s + 4);
            C[rd] = s[6];
        }
        __builtin_amdgcn_sched_barrier(0);          // do not sink loads below
#pragma unroll
        for (int rd = 0; rd < NRD; ++rd) {
            if (rd < 12 || tid < NROWS - 12 * TPB) {    // rd 12: 64 rows only
                const int idx = tid + rd * TPB;
                const int p = idx / 49, r = idx - p * 49;
                uint4 q;
                q.x = pkh(A[rd].x, A[rd].y); q.y = pkh(A[rd].z, A[rd].w);
                q.z = pkh(B[rd].x, B[rd].y); q.w = pkh(C[rd], 0.f);
                *reinterpret_cast<uint4*>(tdw + p * PATCH_D + r * 4) = q;
            }
        }
    }
    __syncthreads();

    // ===================== per-thread conv1+conv2 (4-way task split) ========
    const unsigned int* __restrict__ P =
        reinterpret_cast<const unsigned int*>(sm.tile) + lane * PATCH_D;
    const float bb1 = b1[0];

    float a2[3][3][3];
    {
        const float init = (wid == 0) ? b2[0] : 0.f;   // bias added exactly once
#pragma unroll
        for (int a = 0; a < 3; ++a)
#pragma unroll
            for (int b = 0; b < 3; ++b)
#pragma unroll
                for (int c = 0; c < 3; ++c) a2[a][b][c] = init;
    }

    if      (wid == 0) run_tasks<0, 0, 1, 1>(P, w1, bb1, w2, a2);  // 7 tasks
    else if (wid == 1) run_tasks<1, 2, 2, 3>(P, w1, bb1, w2, a2);  // 7 tasks
    else if (wid == 2) run_tasks<2, 4, 3, 4>(P, w1, bb1, w2, a2);  // 6 tasks
    else               run_tasks<4, 0, 4, 4>(P, w1, bb1, w2, a2);  // 5 tasks

    __syncthreads();     // all tile reads complete before aliasing the union

    // ---- ALL waves write partials ----
#pragma unroll
    for (int t = 0; t < 27; ++t)
        sm.c.part[wid][lane][t] = a2[t / 9][(t / 3) % 3][t % 3];
    __syncthreads();

    // ---- distributed combine: wave w handles taps [7w, 7w+tcnt) ----
    {
        float num = 0.f, den = 0.f;
#pragma unroll
        for (int k = 0; k < 7; ++k) {
            if (k < tcnt) {
                const int tt = t0 + k;
                const float r2 = fmaxf(sm.c.part[0][lane][tt]
                                       + sm.c.part[1][lane][tt]
                                       + sm.c.part[2][lane][tt]
                                       + sm.c.part[3][lane][tt], 0.f);
                const float wt = fmaf(dom[tt], r2, 1e-10f);
                num = fmaf(wt, xv[k], num);
                den += wt;
            }
        }
        sm.c.nd[wid][lane][0] = num;
        sm.c.nd[wid][lane][1] = den;
    }
    __syncthreads();

    // ---- final reduce + divide (wave 0) ----
    if (wid == 0) {
        const float num = sm.c.nd[0][lane][0] + sm.c.nd[1][lane][0]
                        + sm.c.nd[2][lane][0] + sm.c.nd[3][lane][0];
        const float den = sm.c.nd[0][lane][1] + sm.c.nd[1][lane][1]
                        + sm.c.nd[2][lane][1] + sm.c.nd[3][lane][1];
        out[n] = num / den;
    }
}

extern "C" void kernel_launch(void* const* d_in, const int* in_sizes, int n_in,
                              void* d_out, int out_size, void* d_ws, size_t ws_size,
                              hipStream_t stream) {
    const float* x     = (const float*)d_in[0];
    const float* dn    = (const float*)d_in[1];
    const float* guide = (const float*)d_in[2];
    const float* w1_d  = (const float*)d_in[3];
    const float* b1_d  = (const float*)d_in[4];
    const float* w2_d  = (const float*)d_in[5];
    const float* b2_d  = (const float*)d_in[6];
    const float* w1_r  = (const float*)d_in[7];
    const float* b1_r  = (const float*)d_in[8];
    const float* w2_r  = (const float*)d_in[9];
    const float* b2_r  = (const float*)d_in[10];
    float* out = (float*)d_out;
    float* dom = (float*)d_ws;   // 27 floats of scratch

    domain_branch_kernel<<<1, 128, 0, stream>>>(dn, w1_d, b1_d, w2_d, b2_d, dom);
    jbf_main_kernel<<<NBLK, TPB, 0, stream>>>(guide, x, w1_r, b1_r, w2_r,
                                              b2_r, dom, out);
}